// Round 3
// baseline (5583.874 us; speedup 1.0000x reference)
//
#include <hip/hip_runtime.h>
#include <hip/hip_cooperative_groups.h>
#include <cstdint>

namespace cg = cooperative_groups;

typedef __attribute__((ext_vector_type(8))) short bf16x8;
typedef __attribute__((ext_vector_type(4))) float f32x4;
typedef unsigned short u16;

// ---------- bf16 helpers (round-to-nearest-even) ----------
__device__ __forceinline__ u16 f2bf(float x) {
  unsigned u = __builtin_bit_cast(unsigned, x);
  return (u16)((u + 0x7FFFu + ((u >> 16) & 1u)) >> 16);
}
__device__ __forceinline__ float bf2f(u16 h) {
  unsigned u = ((unsigned)h) << 16;
  return __builtin_bit_cast(float, u);
}
__device__ __forceinline__ f32x4 mfma16(bf16x8 a, bf16x8 b, f32x4 c) {
  return __builtin_amdgcn_mfma_f32_16x16x32_bf16(a, b, c, 0, 0, 0);
}

// Packed MFMA-fragment index for Mat[r][k]: frag=(r>>4)*KC+(k>>5), lane=((k&31)>>3)<<4|(r&15), j=k&7
__device__ __forceinline__ size_t pidx(int r, int k, int KC) {
  return ((size_t)((r >> 4) * KC + (k >> 5))) * 512 +
         (size_t)(((((k & 31) >> 3) << 4) | (r & 15)) * 8) + (size_t)(k & 7);
}

// ---------- setup kernels: round + PACK ----------
__global__ void k_round(const float* __restrict__ whh, const float* __restrict__ wun,
                        u16* __restrict__ whhp, u16* __restrict__ wunp) {
  int i = blockIdx.x * 256 + threadIdx.x, st = 1024 * 256;
  for (int j = i; j < 3072 * 1024; j += st) {
    int r = j >> 10, k = j & 1023;
    whhp[pidx(r, k, 32)] = f2bf(whh[j]);
  }
  for (int j = i; j < 256 * 1024; j += st) {
    int r = j >> 10, k = j & 1023;
    wunp[pidx(r, k, 32)] = f2bf(wun[j]);
  }
}

__global__ void k_hinit(const float* __restrict__ c, u16* __restrict__ hhi,
                        u16* __restrict__ hlo) {
  int i = blockIdx.x * 256 + threadIdx.x;  // 262144
  int b = i >> 10, e = i & 1023;
  float v = c[i];
  u16 hi = f2bf(v);
  size_t o = pidx(b, e, 32);
  hhi[o] = hi;
  hlo[o] = f2bf(v - bf2f(hi));
}

// W_comb = W_ih @ W_tok -> packed bf16 frags (KC=8)
__global__ void k_wcomb(const float* __restrict__ wih, const float* __restrict__ wtok,
                        u16* __restrict__ wcb) {
  __shared__ float la[64][33];
  __shared__ float lb[32][65];
  int i0 = blockIdx.x << 6, j0 = blockIdx.y << 6;
  int tid = threadIdx.x;
  int ty = tid >> 4, tx = tid & 15;
  float acc[4][4] = {};
  for (int k0 = 0; k0 < 1024; k0 += 32) {
    __syncthreads();
#pragma unroll
    for (int i = 0; i < 8; ++i) {
      int r = (tid >> 5) + i * 8, cc = tid & 31;
      la[r][cc] = wih[(size_t)(i0 + r) * 1024 + k0 + cc];
    }
#pragma unroll
    for (int i = 0; i < 8; ++i) {
      int idx = i * 256 + tid;
      int r = idx >> 6, cc = idx & 63;
      lb[r][cc] = wtok[(size_t)(k0 + r) * 256 + j0 + cc];
    }
    __syncthreads();
#pragma unroll
    for (int kk = 0; kk < 32; ++kk) {
      float av[4], bv[4];
#pragma unroll
      for (int ii = 0; ii < 4; ++ii) av[ii] = la[ty * 4 + ii][kk];
#pragma unroll
      for (int jj = 0; jj < 4; ++jj) bv[jj] = lb[kk][tx * 4 + jj];
#pragma unroll
      for (int ii = 0; ii < 4; ++ii)
#pragma unroll
        for (int jj = 0; jj < 4; ++jj) acc[ii][jj] += av[ii] * bv[jj];
    }
  }
#pragma unroll
  for (int ii = 0; ii < 4; ++ii)
#pragma unroll
    for (int jj = 0; jj < 4; ++jj)
      wcb[pidx(i0 + ty * 4 + ii, j0 + tx * 4 + jj, 8)] = f2bf(acc[ii][jj]);
}

__global__ void k_bcomb(const float* __restrict__ wih, const float* __restrict__ btok,
                        const float* __restrict__ bih, float* __restrict__ bc) {
  __shared__ float red[256];
  int j = blockIdx.x, t = threadIdx.x;
  float s = 0.f;
  for (int e = t; e < 1024; e += 256) s += wih[(size_t)j * 1024 + e] * btok[e];
  red[t] = s;
  __syncthreads();
  for (int off = 128; off > 0; off >>= 1) {
    if (t < off) red[t] += red[t + off];
    __syncthreads();
  }
  if (t == 0) bc[j] = red[0] + bih[j];
}

// x packed per step-slice (KC=8): slice k holds x[:, :, 127+k] for k in [1,128)
__global__ void k_xprep(const float* __restrict__ x, u16* __restrict__ xhi,
                        u16* __restrict__ xlo) {
  __shared__ float t[64][129];
  int bid = blockIdx.x;
  int b = bid >> 2, d0 = (bid & 3) << 6;
  int tid = threadIdx.x;
#pragma unroll
  for (int i = 0; i < 32; ++i) {
    int idx = i * 256 + tid;
    int dd = idx >> 7, tt = idx & 127;
    t[dd][tt] = x[(size_t)b * 65536 + (size_t)(d0 + dd) * 256 + 128 + tt];
  }
  __syncthreads();
#pragma unroll
  for (int i = 0; i < 32; ++i) {
    int idx = i * 256 + tid;
    int dd = idx & 63, kk = idx >> 6;
    if (kk < 127) {
      float v = t[dd][kk];
      u16 hi = f2bf(v);
      size_t o = (size_t)(kk + 1) * 65536 + pidx(b, d0 + dd, 8);
      xhi[o] = hi;
      xlo[o] = f2bf(v - bf2f(hi));
    }
  }
}

// ---------- persistent cooperative recurrence ----------
// 256 WGs (1/CU). WG (mt=bid&3, et=bid>>2): m-rows [mt*64,+64), gate-cols e in [et*16,+16) all 4 planes.
// W_hh (3x32 frags) + W_comb (3x8 frags) LDS-resident. h/x streamed as packed frags.
__launch_bounds__(256, 1)
__global__ void k_persist(u16* __restrict__ hhi, u16* __restrict__ hlo,
                          const u16* __restrict__ xhi, const u16* __restrict__ xlo,
                          const u16* __restrict__ whhp, const u16* __restrict__ wcp,
                          const float* __restrict__ bih, const float* __restrict__ bc,
                          const float* __restrict__ bhh, u16* __restrict__ ys) {
  __shared__ __align__(16) u16 lwh[3][32][512];  // 96KB
  __shared__ __align__(16) u16 lwc[3][8][512];   // 24KB
  __shared__ __align__(16) u16 st_hh[64][16];    // 2KB
  __shared__ __align__(16) u16 st_hl[64][16];    // 2KB

  int bid = blockIdx.x;
  int mt = bid & 3, et = bid >> 2;  // mt: 4 m-tiles, et: 64 e-tiles
  int tid = threadIdx.x;
  int w = tid >> 6, lane = tid & 63, l15 = lane & 15, l4 = lane >> 4;
  int e0 = et << 4, e = e0 + l15;
  int mrowg = mt * 4 + w;  // h row-group of this wave

  // preload W slices into LDS (packed frags, contiguous copy)
  for (int p = 0; p < 3; ++p) {
    const u16* src = whhp + ((size_t)(p * 64 + et) * 32) * 512;
    u16* dst = &lwh[p][0][0];
#pragma unroll
    for (int i = 0; i < 8; ++i) {
      int o = i * 2048 + tid * 8;
      *(uint4*)(dst + o) = *(const uint4*)(src + o);
    }
    const u16* src2 = wcp + ((size_t)(p * 64 + et) * 8) * 512;
    u16* dst2 = &lwc[p][0][0];
#pragma unroll
    for (int i = 0; i < 2; ++i) {
      int o = i * 2048 + tid * 8;
      *(uint4*)(dst2 + o) = *(const uint4*)(src2 + o);
    }
  }
  __syncthreads();

  // per-thread bias constants (col = e)
  float bhr = bhh[e], bhz = bhh[1024 + e], bhn = bhh[2048 + e];
  float bAr = bih[e], bAz = bih[1024 + e], bAn = bih[2048 + e];
  float bBr = bc[e], bBz = bc[1024 + e], bBn = bc[2048 + e];

  cg::grid_group grid = cg::this_grid();

  for (int k = 0; k < 128; ++k) {
    int cur = k & 1, nxt = cur ^ 1;
    const u16* Hh = hhi + (size_t)cur * 262144 + (size_t)mrowg * 16384 + lane * 8;
    const u16* Hl = hlo + (size_t)cur * 262144 + (size_t)mrowg * 16384 + lane * 8;

    // h_old for update (L1-hot: same rows as A-frags)
    float hold[4];
    {
      size_t hb = (size_t)cur * 262144 + ((size_t)(mrowg * 32 + (et >> 1))) * 512 +
                  (size_t)(((et & 1) * 2 + (l15 >> 3)) * 128) + (size_t)(l15 & 7);
#pragma unroll
      for (int j = 0; j < 4; ++j) {
        size_t o = hb + (size_t)((l4 * 4 + j) * 8);
        hold[j] = bf2f(hhi[o]) + bf2f(hlo[o]);
      }
    }

    f32x4 aR0{}, aR1{}, aZ0{}, aZ1{}, aN0{}, aN1{}, aX0{}, aX1{};
#pragma unroll 4
    for (int kc = 0; kc < 32; ++kc) {
      bf16x8 ah = *(const bf16x8*)(Hh + kc * 512);
      bf16x8 al = *(const bf16x8*)(Hl + kc * 512);
      bf16x8 b0 = *(const bf16x8*)(&lwh[0][kc][0] + lane * 8);
      bf16x8 b1 = *(const bf16x8*)(&lwh[1][kc][0] + lane * 8);
      bf16x8 b2 = *(const bf16x8*)(&lwh[2][kc][0] + lane * 8);
      f32x4& aR = (kc & 1) ? aR1 : aR0;
      f32x4& aZ = (kc & 1) ? aZ1 : aZ0;
      f32x4& aN = (kc & 1) ? aN1 : aN0;
      aR = mfma16(ah, b0, aR); aR = mfma16(al, b0, aR);
      aZ = mfma16(ah, b1, aZ); aZ = mfma16(al, b1, aZ);
      aN = mfma16(ah, b2, aN); aN = mfma16(al, b2, aN);
    }
    if (k > 0) {
      const u16* Xh = xhi + (size_t)k * 65536 + (size_t)mrowg * 4096 + lane * 8;
      const u16* Xl = xlo + (size_t)k * 65536 + (size_t)mrowg * 4096 + lane * 8;
#pragma unroll
      for (int kc = 0; kc < 8; ++kc) {
        bf16x8 ah = *(const bf16x8*)(Xh + kc * 512);
        bf16x8 al = *(const bf16x8*)(Xl + kc * 512);
        bf16x8 b0 = *(const bf16x8*)(&lwc[0][kc][0] + lane * 8);
        bf16x8 b1 = *(const bf16x8*)(&lwc[1][kc][0] + lane * 8);
        bf16x8 b2 = *(const bf16x8*)(&lwc[2][kc][0] + lane * 8);
        f32x4& aR = (kc & 1) ? aR1 : aR0;
        f32x4& aZ = (kc & 1) ? aZ1 : aZ0;
        f32x4& aX = (kc & 1) ? aX1 : aX0;
        aR = mfma16(ah, b0, aR); aR = mfma16(al, b0, aR);
        aZ = mfma16(ah, b1, aZ); aZ = mfma16(al, b1, aZ);
        aX = mfma16(ah, b2, aX); aX = mfma16(al, b2, aX);
      }
    }

    float bir = k ? bBr : bAr, biz = k ? bBz : bAz, bin = k ? bBn : bAn;
#pragma unroll
    for (int j = 0; j < 4; ++j) {
      float gr = aR0[j] + aR1[j] + bir + bhr;
      float gz = aZ0[j] + aZ1[j] + biz + bhz;
      float gh = aN0[j] + aN1[j] + bhn;
      float gx = aX0[j] + aX1[j] + bin;
      float r = 1.f / (1.f + __expf(-gr));
      float z = 1.f / (1.f + __expf(-gz));
      float n = 1.f - 2.f / (1.f + __expf(2.f * (gx + r * gh)));
      float h = (1.f - z) * n + z * hold[j];
      u16 hi = f2bf(h);
      int row_rel = w * 16 + l4 * 4 + j;
      st_hh[row_rel][l15] = hi;
      st_hl[row_rel][l15] = f2bf(h - bf2f(hi));
    }
    __syncthreads();

    // packed 16B-chunk stores: h (hi: tid<128, lo: tid>=128) + ys (tid<128)
    {
      int c = tid & 127, row_rel = c >> 1, oct = c & 1;
      int oct_g = (et & 1) * 2 + oct;
      int row = mt * 64 + row_rel;  // = b
      size_t hoff = ((size_t)((mt * 4 + (row_rel >> 4)) * 32 + (et >> 1))) * 512 +
                    (size_t)((oct_g * 16 + (row_rel & 15)) * 8);
      uint4 v = (tid < 128) ? *(const uint4*)&st_hh[row_rel][oct * 8]
                            : *(const uint4*)&st_hl[row_rel][oct * 8];
      u16* hdst = ((tid < 128) ? hhi : hlo) + (size_t)nxt * 262144;
      *(uint4*)(hdst + hoff) = v;
      if (tid < 128) {
        size_t yoff = ((size_t)((row * 8 + (k >> 4)) * 32 + (et >> 1))) * 512 +
                      (size_t)((oct_g * 16 + (k & 15)) * 8);
        *(uint4*)(ys + yoff) = *(const uint4*)&st_hh[row_rel][oct * 8];
      }
    }
    grid.sync();
  }
}

// ---------- untokenizer: packed ys (A) x packed wun (B, LDS) -> out[b][d][kk] ----------
__launch_bounds__(256, 1)
__global__ void k_untok2(const u16* __restrict__ ysp, const u16* __restrict__ wunp,
                         const float* __restrict__ bun, float* __restrict__ out) {
  __shared__ __align__(16) u16 lwb[4][32][512];  // 128KB: d-slice B frags
  __shared__ float st[64][66];                   // 16.5KB staged output
  int bid = blockIdx.x;
  int nt4 = bid & 3, mtile = bid >> 2;  // 4 d-tiles x 512 row-tiles
  int d0 = nt4 << 6;
  int row0 = mtile << 6;
  int b = mtile >> 1, kk0 = (mtile & 1) << 6;
  int tid = threadIdx.x, w = tid >> 6, lane = tid & 63, l15 = lane & 15, l4 = lane >> 4;

  {
    const u16* src = wunp + ((size_t)(d0 >> 4)) * 32 * 512;
    u16* dst = &lwb[0][0][0];
#pragma unroll
    for (int i = 0; i < 32; ++i) {
      int o = i * 2048 + tid * 8;
      *(uint4*)(dst + o) = *(const uint4*)(src + o);
    }
  }
  __syncthreads();

  int rg = (row0 >> 4) + w;
  const u16* A = ysp + ((size_t)rg * 32) * 512 + lane * 8;
  f32x4 acc[4] = {};
#pragma unroll 4
  for (int kc = 0; kc < 32; ++kc) {
    bf16x8 a = *(const bf16x8*)(A + (size_t)kc * 512);
#pragma unroll
    for (int nt = 0; nt < 4; ++nt) {
      bf16x8 bb = *(const bf16x8*)(&lwb[nt][kc][0] + lane * 8);
      acc[nt] = mfma16(a, bb, acc[nt]);
    }
  }
#pragma unroll
  for (int nt = 0; nt < 4; ++nt)
#pragma unroll
    for (int j = 0; j < 4; ++j)
      st[w * 16 + l4 * 4 + j][nt * 16 + l15] = acc[nt][j];
  __syncthreads();

  int d_rel = tid >> 2, c4 = tid & 3;
  float bv = bun[d0 + d_rel];
  float* orow = out + (size_t)b * 32768 + (size_t)(d0 + d_rel) * 128 + kk0;
#pragma unroll
  for (int rep = 0; rep < 4; ++rep) {
    int kb = (c4 * 4 + rep) * 4;
    float4 v = {st[kb][d_rel] + bv, st[kb + 1][d_rel] + bv,
                st[kb + 2][d_rel] + bv, st[kb + 3][d_rel] + bv};
    *(float4*)(orow + kb) = v;
  }
}

// ---------- launch ----------
extern "C" void kernel_launch(void* const* d_in, const int* in_sizes, int n_in,
                              void* d_out, int out_size, void* d_ws, size_t ws_size,
                              hipStream_t stream) {
  const float* c_in = (const float*)d_in[0];
  const float* x_in = (const float*)d_in[2];
  const float* Wih  = (const float*)d_in[3];
  const float* Whh  = (const float*)d_in[4];
  const float* bih  = (const float*)d_in[5];
  const float* bhh  = (const float*)d_in[6];
  const float* Wtok = (const float*)d_in[7];
  const float* btok = (const float*)d_in[8];
  const float* Wun  = (const float*)d_in[9];
  const float* bun  = (const float*)d_in[10];
  float* out = (float*)d_out;
  char* ws = (char*)d_ws;

  const size_t OW_HH = 0;                     // u16 packed [6144][512]
  const size_t OW_C  = 6291456;               // u16 packed [1536][512]
  const size_t OW_UN = 7864320;               // u16 packed [512][512]
  const size_t OBC   = 8388608;               // f32 [3072]
  const size_t OXHI  = 8400896;               // u16 [128][65536] packed slices
  const size_t OXLO  = 25178112;
  const size_t OHHI  = 41955328;              // u16 [2][524288] packed
  const size_t OHLO  = 43003904;
  const size_t OYS   = 44052480;              // u16 [65536 frags][512] packed
  const size_t NEED  = 111161344;
  if (ws_size < NEED) return;

  u16* whh_p = (u16*)(ws + OW_HH);
  u16* wc_p  = (u16*)(ws + OW_C);
  u16* wun_p = (u16*)(ws + OW_UN);
  float* bc  = (float*)(ws + OBC);
  u16* xhi   = (u16*)(ws + OXHI);
  u16* xlo   = (u16*)(ws + OXLO);
  u16* hhi   = (u16*)(ws + OHHI);
  u16* hlo   = (u16*)(ws + OHLO);
  u16* ys    = (u16*)(ws + OYS);

  k_round<<<1024, 256, 0, stream>>>(Whh, Wun, whh_p, wun_p);
  k_wcomb<<<dim3(48, 4), 256, 0, stream>>>(Wih, Wtok, wc_p);
  k_bcomb<<<3072, 256, 0, stream>>>(Wih, btok, bih, bc);
  k_xprep<<<1024, 256, 0, stream>>>(x_in, xhi, xlo);
  k_hinit<<<1024, 256, 0, stream>>>(c_in, hhi, hlo);

  {
    const float* bih_l = bih;
    const float* bc_l = bc;
    const float* bhh_l = bhh;
    const u16* xhi_l = xhi;
    const u16* xlo_l = xlo;
    const u16* whh_l = whh_p;
    const u16* wc_l = wc_p;
    u16* hhi_l = hhi;
    u16* hlo_l = hlo;
    u16* ys_l = ys;
    void* args[] = {&hhi_l, &hlo_l, &xhi_l, &xlo_l, &whh_l, &wc_l,
                    &bih_l, &bc_l, &bhh_l, &ys_l};
    hipLaunchCooperativeKernel((const void*)k_persist, dim3(256), dim3(256), args, 0, stream);
  }

  k_untok2<<<2048, 256, 0, stream>>>(ys, wun_p, bun, out);
}

// Round 4
// 1681.452 us; speedup vs baseline: 3.3209x; 3.3209x over previous
//
#include <hip/hip_runtime.h>
#include <cstdint>

typedef __attribute__((ext_vector_type(8))) short bf16x8;
typedef __attribute__((ext_vector_type(4))) float f32x4;
typedef unsigned short u16;

// ---------- bf16 helpers (round-to-nearest-even) ----------
__device__ __forceinline__ u16 f2bf(float x) {
  unsigned u = __builtin_bit_cast(unsigned, x);
  return (u16)((u + 0x7FFFu + ((u >> 16) & 1u)) >> 16);
}
__device__ __forceinline__ float bf2f(u16 h) {
  unsigned u = ((unsigned)h) << 16;
  return __builtin_bit_cast(float, u);
}
__device__ __forceinline__ f32x4 mfma16(bf16x8 a, bf16x8 b, f32x4 c) {
  return __builtin_amdgcn_mfma_f32_16x16x32_bf16(a, b, c, 0, 0, 0);
}

// Packed MFMA-fragment index for Mat[r][k]: frag=(r>>4)*KC+(k>>5), lane=((k&31)>>3)<<4|(r&15), j=k&7
__device__ __forceinline__ size_t pidx(int r, int k, int KC) {
  return ((size_t)((r >> 4) * KC + (k >> 5))) * 512 +
         (size_t)(((((k & 31) >> 3) << 4) | (r & 15)) * 8) + (size_t)(k & 7);
}
// plane-triple interleaved gate row: orig (p, e) -> ((e>>4)*3+p)*16 + (e&15)
__device__ __forceinline__ int rowperm(int p, int e) {
  return (((e >> 4) * 3 + p) << 4) + (e & 15);
}

// ---------- setup kernels ----------
__global__ void k_round(const float* __restrict__ whh, const float* __restrict__ wun,
                        u16* __restrict__ whhp, u16* __restrict__ wunp) {
  int i = blockIdx.x * 256 + threadIdx.x, st = 1024 * 256;
  for (int j = i; j < 3072 * 1024; j += st) {
    int r = j >> 10, k = j & 1023;
    int p = r >> 10, e = r & 1023;
    whhp[pidx(rowperm(p, e), k, 32)] = f2bf(whh[j]);
  }
  for (int j = i; j < 256 * 1024; j += st) {
    int r = j >> 10, k = j & 1023;
    wunp[pidx(r, k, 32)] = f2bf(wun[j]);
  }
}

__global__ void k_hinit(const float* __restrict__ c, u16* __restrict__ hhi,
                        u16* __restrict__ hlo) {
  int i = blockIdx.x * 256 + threadIdx.x;  // 262144
  int b = i >> 10, e = i & 1023;
  float v = c[i];
  u16 hi = f2bf(v);
  size_t o = pidx(b, e, 32);
  hhi[o] = hi;
  hlo[o] = f2bf(v - bf2f(hi));
}

// W_comb = W_ih @ W_tok -> packed bf16 frags (KC=8), plane-interleaved rows
__global__ void k_wcomb(const float* __restrict__ wih, const float* __restrict__ wtok,
                        u16* __restrict__ wcb) {
  __shared__ float la[64][33];
  __shared__ float lb[32][65];
  int i0 = blockIdx.x << 6, j0 = blockIdx.y << 6;
  int tid = threadIdx.x;
  int ty = tid >> 4, tx = tid & 15;
  float acc[4][4] = {};
  for (int k0 = 0; k0 < 1024; k0 += 32) {
    __syncthreads();
#pragma unroll
    for (int i = 0; i < 8; ++i) {
      int r = (tid >> 5) + i * 8, cc = tid & 31;
      la[r][cc] = wih[(size_t)(i0 + r) * 1024 + k0 + cc];
    }
#pragma unroll
    for (int i = 0; i < 8; ++i) {
      int idx = i * 256 + tid;
      int r = idx >> 6, cc = idx & 63;
      lb[r][cc] = wtok[(size_t)(k0 + r) * 256 + j0 + cc];
    }
    __syncthreads();
#pragma unroll
    for (int kk = 0; kk < 32; ++kk) {
      float av[4], bv[4];
#pragma unroll
      for (int ii = 0; ii < 4; ++ii) av[ii] = la[ty * 4 + ii][kk];
#pragma unroll
      for (int jj = 0; jj < 4; ++jj) bv[jj] = lb[kk][tx * 4 + jj];
#pragma unroll
      for (int ii = 0; ii < 4; ++ii)
#pragma unroll
        for (int jj = 0; jj < 4; ++jj) acc[ii][jj] += av[ii] * bv[jj];
    }
  }
#pragma unroll
  for (int ii = 0; ii < 4; ++ii)
#pragma unroll
    for (int jj = 0; jj < 4; ++jj) {
      int r = i0 + ty * 4 + ii;
      int p = r >> 10, e = r & 1023;
      wcb[pidx(rowperm(p, e), j0 + tx * 4 + jj, 8)] = f2bf(acc[ii][jj]);
    }
}

__global__ void k_bcomb(const float* __restrict__ wih, const float* __restrict__ btok,
                        const float* __restrict__ bih, float* __restrict__ bc) {
  __shared__ float red[256];
  int j = blockIdx.x, t = threadIdx.x;
  float s = 0.f;
  for (int e = t; e < 1024; e += 256) s += wih[(size_t)j * 1024 + e] * btok[e];
  red[t] = s;
  __syncthreads();
  for (int off = 128; off > 0; off >>= 1) {
    if (t < off) red[t] += red[t + off];
    __syncthreads();
  }
  if (t == 0) bc[j] = red[0] + bih[j];
}

// x packed per step-slice (KC=8): slice k holds x[:, :, 127+k] for k in [1,128)
__global__ void k_xprep(const float* __restrict__ x, u16* __restrict__ xhi,
                        u16* __restrict__ xlo) {
  __shared__ float t[64][129];
  int bid = blockIdx.x;
  int b = bid >> 2, d0 = (bid & 3) << 6;
  int tid = threadIdx.x;
#pragma unroll
  for (int i = 0; i < 32; ++i) {
    int idx = i * 256 + tid;
    int dd = idx >> 7, tt = idx & 127;
    t[dd][tt] = x[(size_t)b * 65536 + (size_t)(d0 + dd) * 256 + 128 + tt];
  }
  __syncthreads();
#pragma unroll
  for (int i = 0; i < 32; ++i) {
    int idx = i * 256 + tid;
    int dd = idx & 63, kk = idx >> 6;
    if (kk < 127) {
      float v = t[dd][kk];
      u16 hi = f2bf(v);
      size_t o = (size_t)(kk + 1) * 65536 + pidx(b, d0 + dd, 8);
      xhi[o] = hi;
      xlo[o] = f2bf(v - bf2f(hi));
    }
  }
}

// ---------- per-step fused kernel ----------
// 256 WGs x 512 thr. WG tile: [32 m-rows x 32 e-cols x {r,z,n}] ; waves: (ws K-half, ms, es).
__launch_bounds__(512, 1)
__global__ void k_step3(const u16* __restrict__ hhi, const u16* __restrict__ hlo,
                        const u16* __restrict__ xhi, const u16* __restrict__ xlo,
                        const u16* __restrict__ whp, const u16* __restrict__ wcp,
                        const float* __restrict__ bgi, const float* __restrict__ bhh,
                        u16* __restrict__ nhhi, u16* __restrict__ nhlo,
                        u16* __restrict__ ys, int use_x, int kstep) {
  __shared__ __align__(16) float red[2][2][4][256];  // [ms][es][gate][frag f32] 16KB

  int bid = blockIdx.x;
  int xcd = bid & 7, g = bid >> 3;
  int et = xcd * 4 + (g & 3);  // 0..31  (XCD-pinned e-slices)
  int mt = g >> 2;             // 0..7
  int tid = threadIdx.x;
  int w = tid >> 6, lane = tid & 63, l15 = lane & 15, l4 = lane >> 4;
  int ws = w & 1, ms = (w >> 1) & 1, es = w >> 2;  // es 0..1

  int mf = mt * 2 + ms;            // m-frag (16 b-rows)
  int eb = et * 2 + es;            // 16e-block index 0..63
  int rf0 = eb * 3;                // W' frag rows for planes r,z,n

  const u16* Ah = hhi + ((size_t)mf * 32) * 512 + lane * 8;
  const u16* Al = hlo + ((size_t)mf * 32) * 512 + lane * 8;
  const u16* B0 = whp + ((size_t)(rf0 + 0) * 32) * 512 + lane * 8;
  const u16* B1 = whp + ((size_t)(rf0 + 1) * 32) * 512 + lane * 8;
  const u16* B2 = whp + ((size_t)(rf0 + 2) * 32) * 512 + lane * 8;

  f32x4 aRh{}, aRl{}, aZh{}, aZl{}, aNh{}, aNl{}, aXh{}, aXl{};

#pragma unroll 4
  for (int kc = ws * 16; kc < ws * 16 + 16; ++kc) {
    bf16x8 ah = *(const bf16x8*)(Ah + (size_t)kc * 512);
    bf16x8 al = *(const bf16x8*)(Al + (size_t)kc * 512);
    bf16x8 b0 = *(const bf16x8*)(B0 + (size_t)kc * 512);
    bf16x8 b1 = *(const bf16x8*)(B1 + (size_t)kc * 512);
    bf16x8 b2 = *(const bf16x8*)(B2 + (size_t)kc * 512);
    aRh = mfma16(ah, b0, aRh); aRl = mfma16(al, b0, aRl);
    aZh = mfma16(ah, b1, aZh); aZl = mfma16(al, b1, aZl);
    aNh = mfma16(ah, b2, aNh); aNl = mfma16(al, b2, aNl);
  }
  if (use_x) {
    const u16* Xh = xhi + ((size_t)mf * 8) * 512 + lane * 8;
    const u16* Xl = xlo + ((size_t)mf * 8) * 512 + lane * 8;
    const u16* C0 = wcp + ((size_t)(rf0 + 0) * 8) * 512 + lane * 8;
    const u16* C1 = wcp + ((size_t)(rf0 + 1) * 8) * 512 + lane * 8;
    const u16* C2 = wcp + ((size_t)(rf0 + 2) * 8) * 512 + lane * 8;
#pragma unroll
    for (int kc = ws * 4; kc < ws * 4 + 4; ++kc) {
      bf16x8 ah = *(const bf16x8*)(Xh + (size_t)kc * 512);
      bf16x8 al = *(const bf16x8*)(Xl + (size_t)kc * 512);
      bf16x8 b0 = *(const bf16x8*)(C0 + (size_t)kc * 512);
      bf16x8 b1 = *(const bf16x8*)(C1 + (size_t)kc * 512);
      bf16x8 b2 = *(const bf16x8*)(C2 + (size_t)kc * 512);
      aRh = mfma16(ah, b0, aRh); aRl = mfma16(al, b0, aRl);
      aZh = mfma16(ah, b1, aZh); aZl = mfma16(al, b1, aZl);
      aXh = mfma16(ah, b2, aXh); aXl = mfma16(al, b2, aXl);
    }
  }

  if (ws == 1) {
    f32x4 vR = aRh + aRl, vZ = aZh + aZl, vN = aNh + aNl, vX = aXh + aXl;
    *(f32x4*)&red[ms][es][0][lane * 4] = vR;
    *(f32x4*)&red[ms][es][1][lane * 4] = vZ;
    *(f32x4*)&red[ms][es][2][lane * 4] = vN;
    *(f32x4*)&red[ms][es][3][lane * 4] = vX;
  }
  __syncthreads();
  if (ws == 0) {
    f32x4 vR = aRh + aRl + *(const f32x4*)&red[ms][es][0][lane * 4];
    f32x4 vZ = aZh + aZl + *(const f32x4*)&red[ms][es][1][lane * 4];
    f32x4 vN = aNh + aNl + *(const f32x4*)&red[ms][es][2][lane * 4];
    f32x4 vX = aXh + aXl + *(const f32x4*)&red[ms][es][3][lane * 4];

    int e = eb * 16 + l15;
    float br = bgi[e] + bhh[e];
    float bz = bgi[1024 + e] + bhh[1024 + e];
    float bnh = bhh[2048 + e];
    float bnx = bgi[2048 + e];
    int lanepart = ((((e & 31) >> 3) << 4));  // e-octet selector within frag
    int e7 = e & 7;

#pragma unroll
    for (int j = 0; j < 4; ++j) {
      int b = mf * 16 + l4 * 4 + j;
      size_t ho = ((size_t)(mf * 32 + (e >> 5))) * 512 +
                  (size_t)((lanepart | (b & 15)) * 8) + (size_t)e7;
      float hold = bf2f(hhi[ho]) + bf2f(hlo[ho]);
      float gr = vR[j] + br;
      float gz = vZ[j] + bz;
      float gh = vN[j] + bnh;
      float gx = vX[j] + bnx;
      float r = 1.f / (1.f + __expf(-gr));
      float z = 1.f / (1.f + __expf(-gz));
      float n = 1.f - 2.f / (1.f + __expf(2.f * (gx + r * gh)));
      float h = (1.f - z) * n + z * hold;
      u16 hi = f2bf(h);
      nhhi[ho] = hi;
      nhlo[ho] = f2bf(h - bf2f(hi));
      int row = b * 128 + kstep;
      size_t yo = ((size_t)((row >> 4) * 32 + (e >> 5))) * 512 +
                  (size_t)((lanepart | (kstep & 15)) * 8) + (size_t)e7;
      ys[yo] = hi;
    }
  }
}

// ---------- untokenizer: packed ys (A) x packed wun (B, LDS) -> out[b][d][kk] ----------
__launch_bounds__(256, 1)
__global__ void k_untok2(const u16* __restrict__ ysp, const u16* __restrict__ wunp,
                         const float* __restrict__ bun, float* __restrict__ out) {
  __shared__ __align__(16) u16 lwb[4][32][512];  // 128KB: d-slice B frags
  __shared__ float st[64][66];                   // staged output
  int bid = blockIdx.x;
  int nt4 = bid & 3, mtile = bid >> 2;
  int d0 = nt4 << 6;
  int row0 = mtile << 6;
  int b = mtile >> 1, kk0 = (mtile & 1) << 6;
  int tid = threadIdx.x, w = tid >> 6, lane = tid & 63, l15 = lane & 15, l4 = lane >> 4;

  {
    const u16* src = wunp + ((size_t)(d0 >> 4)) * 32 * 512;
    u16* dst = &lwb[0][0][0];
#pragma unroll
    for (int i = 0; i < 32; ++i) {
      int o = i * 2048 + tid * 8;
      *(uint4*)(dst + o) = *(const uint4*)(src + o);
    }
  }
  __syncthreads();

  int rg = (row0 >> 4) + w;
  const u16* A = ysp + ((size_t)rg * 32) * 512 + lane * 8;
  f32x4 acc[4] = {};
#pragma unroll 4
  for (int kc = 0; kc < 32; ++kc) {
    bf16x8 a = *(const bf16x8*)(A + (size_t)kc * 512);
#pragma unroll
    for (int nt = 0; nt < 4; ++nt) {
      bf16x8 bb = *(const bf16x8*)(&lwb[nt][kc][0] + lane * 8);
      acc[nt] = mfma16(a, bb, acc[nt]);
    }
  }
#pragma unroll
  for (int nt = 0; nt < 4; ++nt)
#pragma unroll
    for (int j = 0; j < 4; ++j)
      st[w * 16 + l4 * 4 + j][nt * 16 + l15] = acc[nt][j];
  __syncthreads();

  int d_rel = tid >> 2, c4 = tid & 3;
  float bv = bun[d0 + d_rel];
  float* orow = out + (size_t)b * 32768 + (size_t)(d0 + d_rel) * 128 + kk0;
#pragma unroll
  for (int rep = 0; rep < 4; ++rep) {
    int kb = (c4 * 4 + rep) * 4;
    float4 v = {st[kb][d_rel] + bv, st[kb + 1][d_rel] + bv,
                st[kb + 2][d_rel] + bv, st[kb + 3][d_rel] + bv};
    *(float4*)(orow + kb) = v;
  }
}

// ---------- launch ----------
extern "C" void kernel_launch(void* const* d_in, const int* in_sizes, int n_in,
                              void* d_out, int out_size, void* d_ws, size_t ws_size,
                              hipStream_t stream) {
  const float* c_in = (const float*)d_in[0];
  const float* x_in = (const float*)d_in[2];
  const float* Wih  = (const float*)d_in[3];
  const float* Whh  = (const float*)d_in[4];
  const float* bih  = (const float*)d_in[5];
  const float* bhh  = (const float*)d_in[6];
  const float* Wtok = (const float*)d_in[7];
  const float* btok = (const float*)d_in[8];
  const float* Wun  = (const float*)d_in[9];
  const float* bun  = (const float*)d_in[10];
  float* out = (float*)d_out;
  char* ws = (char*)d_ws;

  const size_t OW_HH = 0;                     // u16 packed [6144 frags][512]
  const size_t OW_C  = 6291456;               // u16 packed [1536 frags][512]
  const size_t OW_UN = 7864320;               // u16 packed [512 frags][512]
  const size_t OBC   = 8388608;               // f32 [3072]
  const size_t OXHI  = 8400896;               // u16 [128][65536]
  const size_t OXLO  = 25178112;
  const size_t OHHI  = 41955328;              // u16 [2][262144]
  const size_t OHLO  = 43003904;
  const size_t OYS   = 44052480;              // u16 packed [65536 frags][512]... (b*128+kk rows)
  const size_t NEED  = 111161344;
  if (ws_size < NEED) return;

  u16* whh_p = (u16*)(ws + OW_HH);
  u16* wc_p  = (u16*)(ws + OW_C);
  u16* wun_p = (u16*)(ws + OW_UN);
  float* bc  = (float*)(ws + OBC);
  u16* xhi   = (u16*)(ws + OXHI);
  u16* xlo   = (u16*)(ws + OXLO);
  u16* hhi   = (u16*)(ws + OHHI);
  u16* hlo   = (u16*)(ws + OHLO);
  u16* ys    = (u16*)(ws + OYS);

  k_round<<<1024, 256, 0, stream>>>(Whh, Wun, whh_p, wun_p);
  k_wcomb<<<dim3(48, 4), 256, 0, stream>>>(Wih, Wtok, wc_p);
  k_bcomb<<<3072, 256, 0, stream>>>(Wih, btok, bih, bc);
  k_xprep<<<1024, 256, 0, stream>>>(x_in, xhi, xlo);
  k_hinit<<<1024, 256, 0, stream>>>(c_in, hhi, hlo);

  for (int k = 0; k < 128; ++k) {
    int cur = k & 1, nxt = cur ^ 1;
    k_step3<<<256, 512, 0, stream>>>(
        hhi + (size_t)cur * 262144, hlo + (size_t)cur * 262144,
        xhi + (size_t)k * 65536, xlo + (size_t)k * 65536,
        whh_p, wc_p, (k == 0) ? bih : bc, bhh,
        hhi + (size_t)nxt * 262144, hlo + (size_t)nxt * 262144,
        ys, k > 0 ? 1 : 0, k);
  }
  k_untok2<<<2048, 256, 0, stream>>>(ys, wun_p, bun, out);
}